// Round 9
// baseline (76.899 us; speedup 1.0000x reference)
//
#include <hip/hip_runtime.h>
#include <cstdint>

typedef unsigned short u16;
typedef unsigned int u32;
typedef unsigned long long u64;
typedef unsigned short us2 __attribute__((ext_vector_type(2)));

constexpr int BB = 16, HH = 512, WW = 512;
constexpr int NPIX = BB * HH * WW;          // 4,194,304

// workspace layout (bytes)
constexpr size_t D1_OFF  = 0;                     // s8 signed d1 (cap 127), 4 MiB
constexpr size_t ACC_OFF = (size_t)NPIX;          // atomic accumulators (520 B)

// envelope tiling
constexpr int HALO  = 16;                 // vertical halo (deep search cap)
constexpr int XT    = 32;                 // output rows per block
constexpr int TROWS = XT + 2 * HALO;      // 64 tile rows
constexpr int CDW   = TROWS / 2 + 1;      // 33 dwords per padded LDS column
constexpr int NBLK  = (WW / 64) * (HH / XT) * BB; // 2048 k_env blocks

// ---------------- Kernel A: per-row 1D distances (single boundary scan) ------
// d1 = distance to nearest opposite-value pixel in the row (= distance to the
// nearest run boundary), capped at 127. v = t ? +d1 : -d1 stored as s8.
// Block 0 additionally zeroes the accumulator region (visible to k_env via the
// kernel boundary).
__global__ void __launch_bounds__(256) k_rows(const int* __restrict__ tg,
                                              char* __restrict__ d1b,
                                              u32* __restrict__ acc) {
  if (blockIdx.x == 0 && threadIdx.x < 130) acc[threadIdx.x] = 0;

  const int lane = threadIdx.x & 63;
  const int wv   = threadIdx.x >> 6;
  const int row  = blockIdx.x * 4 + wv;        // b*512 + h, 8192 rows
  const int c0   = lane * 8;
  const int* rp  = tg + (size_t)row * WW;
  int4 va = *(const int4*)(rp + c0);
  int4 vb = *(const int4*)(rp + c0 + 4);
  int t[8] = {va.x, va.y, va.z, va.w, vb.x, vb.y, vb.z, vb.w};
  int tprev0 = __shfl_up(t[7], 1);   // lane0 value unused (i==0 case)
  int tnext7 = __shfl_down(t[0], 1); // lane63 value unused (i==511 case)

  // left boundary positions, inclusive prefix max
  int lm[8]; int m = -2048;
  #pragma unroll
  for (int k = 0; k < 8; ++k) {
    int i = c0 + k;
    int tp = (k == 0) ? tprev0 : t[k - 1];
    int c = (i > 0 && t[k] != tp) ? i : -2048;
    m = max(m, c); lm[k] = m;
  }
  int X = m;
  #pragma unroll
  for (int off = 1; off < 64; off <<= 1) {
    int y = __shfl_up(X, off);
    if (lane >= off) X = max(X, y);
  }
  int E = __shfl_up(X, 1); if (lane == 0) E = -2048;

  // right boundary positions, inclusive suffix min
  int sm[8]; m = 2559;
  #pragma unroll
  for (int k = 7; k >= 0; --k) {
    int i = c0 + k;
    int tn = (k == 7) ? tnext7 : t[k + 1];
    int c = (i < 511 && t[k] != tn) ? i : 2559;
    m = min(m, c); sm[k] = m;
  }
  int X2 = m;
  #pragma unroll
  for (int off = 1; off < 64; off <<= 1) {
    int y = __shfl_down(X2, off);
    if (lane + off < 64) X2 = min(X2, y);
  }
  int E2 = __shfl_down(X2, 1); if (lane == 63) E2 = 2559;

  u32 lo = 0, hi = 0;
  #pragma unroll
  for (int k = 0; k < 8; ++k) {
    int i = c0 + k;
    int L = max(lm[k], E), R = min(sm[k], E2);
    int d1 = min(min(i - L + 1, R - i + 1), 127);
    int v = t[k] ? d1 : -d1;
    u32 b8 = (u32)(v & 0xff);
    if (k < 4) lo |= b8 << (8 * k); else hi |= b8 << (8 * (k - 4));
  }
  uint2 o = make_uint2(lo, hi);
  ((uint2*)d1b)[(size_t)row * (WW / 8) + lane] = o;
}

// ------------- Kernel B: column lower-envelope + reductions + finalize -------
// Per-row body, parity P = (tile row) & 1 (compile-time). Window of 8
// consecutive dwords (16 rows) covers dy 1..7 both sides; dy^2 pairs are
// compile-time packed constants; candidates evaluated with packed u16 math.
// Sentinel 127 pads OOB rows (no image-boundary clamping anywhere).
template <int P>
__device__ __forceinline__ void row_body(
    int e, const u32* __restrict__ pc, const u32* __restrict__ nc,
    const float* __restrict__ ip,
    float& aP, float& aTP, float& aS, u32& aM, int& aC) {
  constexpr u16 KL[2][8] = {{64, 36, 16, 4, 0, 4, 16, 36},
                            {49, 25,  9, 1, 1, 9, 25, 49}};
  constexpr u16 KH[2][8] = {{49, 25,  9, 1, 1, 9, 25, 49},
                            {36, 16,  4, 0, 4, 16, 36, 64}};
  const u32 pd = pc[e], nd = nc[e];
  const int vp = (P == 0) ? (int)(pd & 0xffffu) : (int)(pd >> 16);
  const int vn = (P == 0) ? (int)(nd & 0xffffu) : (int)(nd >> 16);
  const bool fg = vp > 0;
  const int uo = max(vp, vn);                  // own-class 1D distance (one is 0)
  const u32* cb = fg ? pc : nc;                // search own-class tile
  const us2* cb2 = (const us2*)cb;
  const int s = e + P - 4;                     // window dwords s..s+7
  us2 bestpk = __builtin_bit_cast(us2, 0xffffffffu);
  #pragma unroll
  for (int i = 0; i < 8; ++i) {
    us2 w = cb2[s + i];
    us2 k = __builtin_bit_cast(us2, (u32)KL[P][i] | ((u32)KH[P][i] << 16));
    us2 cnd = (us2)(w * w + k);
    bestpk = __builtin_elementwise_min(bestpk, cnd);
  }
  u32 best = min((u32)(uo * uo), (u32)min((u32)bestpk[0], (u32)bestpk[1]));
  if (__any(uo > 8)) {                         // rare exact fallback, dy 8..HALO
    const int c = 2 * e + P;
    #pragma unroll 1
    for (int dy = 8; dy <= HALO; ++dy) {
      int rd = c + dy, ru = c - dy;
      u32 dd = cb[rd >> 1], du = cb[ru >> 1];
      int ud = (int)((dd >> ((rd & 1) * 16)) & 0xffffu);
      int uu = (int)((du >> ((ru & 1) * 16)) & 0xffffu);
      int q = dy * dy;
      best = min(best, (u32)(ud * ud + q));
      best = min(best, (u32)(uu * uu + q));
    }
  }
  float D = sqrtf((float)best);                // = posdis+negdis at this pixel
  float v = *ip;
  float p = 1.0f / (1.0f + __expf(-v));
  aP += p;
  if (fg) { aTP += p; aC += 1; aS -= p * D; } else { aS += p * D; }
  aM = max(aM, best);
}

__global__ void __launch_bounds__(256, 8) k_env(const char* __restrict__ d1b,
                                                const float* __restrict__ inp,
                                                char* __restrict__ wsa,
                                                float* __restrict__ out) {
  __shared__ u32 posT[64 * CDW];               // column-major u16, 2 rows/dword
  __shared__ u32 negT[64 * CDW];
  const int tid = threadIdx.x;
  const int cg = blockIdx.x, xt = blockIdx.y, b = blockIdx.z;
  const int w0 = cg * 64, x0 = xt * XT;

  // transposed two-class staging: 256 units = (row-pair r2 0..31) x (c8 0..7)
  {
    int r2 = tid >> 3, c8 = tid & 7;
    int g0 = x0 - HALO + 2 * r2;
    const char* base = d1b + ((size_t)(b * HH)) * WW + w0 + c8 * 8;
    uint2 A = make_uint2(0, 0), Bv = make_uint2(0, 0);
    bool ok0 = (unsigned)g0 < (unsigned)HH;
    bool ok1 = (unsigned)(g0 + 1) < (unsigned)HH;
    if (ok0) A  = *(const uint2*)(base + (size_t)g0 * WW);
    if (ok1) Bv = *(const uint2*)(base + (size_t)(g0 + 1) * WW);
    u32 aw[2] = {A.x, A.y}, bw[2] = {Bv.x, Bv.y};
    #pragma unroll
    for (int j = 0; j < 8; ++j) {
      int sa = ((int)(aw[j >> 2] << ((3 - (j & 3)) * 8))) >> 24;  // sext byte
      int sb = ((int)(bw[j >> 2] << ((3 - (j & 3)) * 8))) >> 24;
      int vpa = ok0 ? max(sa, 0) : 127, vna = ok0 ? max(-sa, 0) : 127;
      int vpb = ok1 ? max(sb, 0) : 127, vnb = ok1 ? max(-sb, 0) : 127;
      int col = c8 * 8 + j;
      posT[col * CDW + r2] = (u32)vpa | ((u32)vpb << 16);
      negT[col * CDW + r2] = (u32)vna | ((u32)vnb << 16);
    }
  }
  __syncthreads();

  const int wv = tid >> 6, lane = tid & 63;
  const u32* pc = posT + lane * CDW;
  const u32* nc = negT + lane * CDW;
  const float* ip0 = inp + ((size_t)(b * HH + x0 + wv * 8)) * WW + w0 + lane;
  float aP = 0.f, aTP = 0.f, aS = 0.f;
  u32 aM = 0; int aC = 0;

  #pragma unroll 1
  for (int k2 = 0; k2 < 4; ++k2) {
    const int e = (HALO + wv * 8) / 2 + k2;    // own row-pair dword index
    row_body<0>(e, pc, nc, ip0 + (size_t)(2 * k2) * WW,     aP, aTP, aS, aM, aC);
    row_body<1>(e, pc, nc, ip0 + (size_t)(2 * k2 + 1) * WW, aP, aTP, aS, aM, aC);
  }

  // wave reduce
  #pragma unroll
  for (int off = 32; off >= 1; off >>= 1) {
    aP  += __shfl_xor(aP, off);
    aTP += __shfl_xor(aTP, off);
    aS  += __shfl_xor(aS, off);
    aC  += __shfl_xor(aC, off);
    aM = max(aM, (u32)__shfl_xor((int)aM, off));
  }
  __shared__ float rP[4], rTP[4], rS[4];
  __shared__ u32 rM[4]; __shared__ int rC[4]; __shared__ int lastF;
  if (lane == 0) { rP[wv] = aP; rTP[wv] = aTP; rS[wv] = aS; rM[wv] = aM; rC[wv] = aC; }
  __syncthreads();

  u64* accS  = (u64*)(wsa);
  u64* accP  = (u64*)(wsa + 128);
  u64* accTP = (u64*)(wsa + 256);
  u32* accM  = (u32*)(wsa + 384);
  int* accT  = (int*)(wsa + 448);
  u32* cnt   = (u32*)(wsa + 512);

  if (tid == 0) {
    float bS  = rS[0] + rS[1] + rS[2] + rS[3];
    float bP  = rP[0] + rP[1] + rP[2] + rP[3];
    float bTP = rTP[0] + rTP[1] + rTP[2] + rTP[3];
    u32 bM = max(max(rM[0], rM[1]), max(rM[2], rM[3]));
    int bC = rC[0] + rC[1] + rC[2] + rC[3];
    // fixed-point (2^16) integer atomics: order-invariant => deterministic
    atomicAdd(&accS[b],  (u64)(long long)__double2ll_rn((double)bS  * 65536.0));
    atomicAdd(&accP[b],  (u64)(long long)__double2ll_rn((double)bP  * 65536.0));
    atomicAdd(&accTP[b], (u64)(long long)__double2ll_rn((double)bTP * 65536.0));
    atomicMax(&accM[b], bM);
    atomicAdd(&accT[b], bC);
    __threadfence();
    u32 old = atomicAdd(cnt, 1u);
    lastF = (old == (u32)(NBLK - 1)) ? 1 : 0;
  }
  __syncthreads();

  // ---- last block finalizes the scalar loss ----
  if (lastF && tid == 0) {
    __threadfence();
    float sumP = 0.f, TP = 0.f, sumT = 0.f, bl = 0.f;
    for (int i = 0; i < 16; ++i) {
      long long sS  = (long long)atomicAdd(&accS[i], 0ull);
      long long sP  = (long long)atomicAdd(&accP[i], 0ull);
      long long sTP = (long long)atomicAdd(&accTP[i], 0ull);
      u32 m2 = atomicMax(&accM[i], 0u);
      int Ti = atomicAdd(&accT[i], 0);
      float S   = (float)((double)sS  / 65536.0);
      float Pi  = (float)((double)sP  / 65536.0);
      float TPi = (float)((double)sTP / 65536.0);
      float bmax = sqrtf((float)m2);
      bl += (Ti > 0) ? (S / (bmax + 1e-8f)) : 0.0f;   // anypos guard
      sumP += Pi; TP += TPi; sumT += (float)Ti;
    }
    float FP = sumP - TP, FN = sumT - TP;
    float tv = (TP + 1.0f) / (TP + 0.3f * FP + 0.7f * FN + 1.0f);
    float ft = powf(fmaxf(1.0f - tv, 0.0f), 1.33f);
    float dice = (2.0f * TP + 1.0f) / (sumP + sumT + 1.0f);
    float dl = 1.0f - dice;
    float blm = bl / (float)NPIX;
    if (isnan(ft)) ft = 0.0f;
    if (isnan(dl)) dl = 0.0f;
    if (isnan(blm)) blm = 0.0f;
    out[0] = 0.5f * ft + 0.3f * dl + 0.2f * blm;
  }
}

extern "C" void kernel_launch(void* const* d_in, const int* in_sizes, int n_in,
                              void* d_out, int out_size, void* d_ws, size_t ws_size,
                              hipStream_t stream) {
  const float* inp = (const float*)d_in[0];
  const int* tg = (const int*)d_in[1];
  float* out = (float*)d_out;
  char* ws = (char*)d_ws;
  char* d1b = (char*)(ws + D1_OFF);
  char* wsa = (char*)(ws + ACC_OFF);

  hipLaunchKernelGGL(k_rows, dim3(BB * HH / 4), dim3(256), 0, stream,
                     tg, d1b, (u32*)wsa);
  hipLaunchKernelGGL(k_env, dim3(WW / 64, HH / XT, BB), dim3(256), 0, stream,
                     d1b, inp, wsa, out);
}

// Round 10
// 29.281 us; speedup vs baseline: 2.6263x; 2.6263x over previous
//
#include <hip/hip_runtime.h>
#include <cstdint>

typedef unsigned short u16;
typedef unsigned int u32;
typedef unsigned short us2 __attribute__((ext_vector_type(2)));

constexpr int BB = 16, HH = 512, WW = 512;
constexpr int NPIX = BB * HH * WW;          // 4,194,304

// workspace layout (bytes)
constexpr size_t D1_OFF   = 0;                    // s8 signed d1 (cap 127), 4 MiB
constexpr size_t PART_OFF = (size_t)NPIX;

// envelope tiling
constexpr int HALO  = 16;                 // vertical halo (deep search cap)
constexpr int XT    = 32;                 // output rows per block
constexpr int TROWS = XT + 2 * HALO;      // 64 tile rows
constexpr int CDW   = TROWS / 2 + 1;      // 33 dwords per padded LDS column

__device__ __forceinline__ us2 pmax2(us2 a, us2 b) { return __builtin_elementwise_max(a, b); }
__device__ __forceinline__ us2 pmin2(us2 a, us2 b) { return __builtin_elementwise_min(a, b); }
__device__ __forceinline__ us2 U2(u32 x) { return __builtin_bit_cast(us2, x); }
__device__ __forceinline__ u32 B2(us2 x) { return __builtin_bit_cast(u32, x); }

// ---------------- Kernel A: packed dual-row 1D boundary scans ----------------
// Two image rows per wave, packed into u16 halves (biased +2048 positions).
// d1 = distance to nearest run boundary, capped 127; v = t ? +d1 : -d1 (s8).
__global__ void __launch_bounds__(256) k_rows(const int* __restrict__ tg,
                                              char* __restrict__ d1b) {
  const int lane = threadIdx.x & 63;
  const int wv   = threadIdx.x >> 6;
  const int rowA = blockIdx.x * 8 + wv * 2;    // 1024 blocks, 2 rows per wave
  const int c0   = lane * 8;
  const int* rpA = tg + (size_t)rowA * WW + c0;
  const int* rpB = rpA + WW;
  int4 a0 = *(const int4*)rpA, a1 = *(const int4*)(rpA + 4);
  int4 b0 = *(const int4*)rpB, b1 = *(const int4*)(rpB + 4);
  int tA[8] = {a0.x, a0.y, a0.z, a0.w, a1.x, a1.y, a1.z, a1.w};
  int tB[8] = {b0.x, b0.y, b0.z, b0.w, b1.x, b1.y, b1.z, b1.w};
  u32 tp[8];
  #pragma unroll
  for (int k = 0; k < 8; ++k) tp[k] = (u32)tA[k] | ((u32)tB[k] << 16);
  u32 tprev = __shfl_up(tp[7], 1);  if (lane == 0)  tprev = tp[0];
  u32 tnext = __shfl_down(tp[0], 1); if (lane == 63) tnext = tp[7];

  // fwd: prefix max of (boundary-at-i ? i+2048 : 0), both rows packed u16
  u32 lm[8]; us2 m = U2(0);
  #pragma unroll
  for (int k = 0; k < 8; ++k) {
    u32 prev = k ? tp[k - 1] : tprev;
    us2 diff = U2(tp[k] ^ prev);               // 0/1 per half (targets are 0/1)
    us2 ib = U2((u32)(c0 + k + 2048) * 0x10001u);
    m = pmax2(m, (us2)(diff * ib));
    lm[k] = B2(m);
  }
  u32 X = B2(m);
  #pragma unroll
  for (int off = 1; off < 64; off <<= 1) {
    u32 y = __shfl_up(X, off);
    if (lane >= off) X = B2(pmax2(U2(X), U2(y)));
  }
  u32 E = __shfl_up(X, 1); if (lane == 0) E = 0;

  // bwd: suffix min of (boundary-at-i ? i+2048 : 4607)
  u32 sm[8]; us2 m2 = U2(0x11ff11ffu);
  #pragma unroll
  for (int k = 7; k >= 0; --k) {
    u32 nxt = (k < 7) ? tp[k + 1] : tnext;
    us2 diff = U2(tp[k] ^ nxt);
    us2 sb = U2((u32)(2559 - (c0 + k)) * 0x10001u);
    m2 = pmin2(m2, (us2)(U2(0x11ff11ffu) - (us2)(diff * sb)));
    sm[k] = B2(m2);
  }
  u32 X2 = B2(m2);
  #pragma unroll
  for (int off = 1; off < 64; off <<= 1) {
    u32 y = __shfl_down(X2, off);
    if (lane + off < 64) X2 = B2(pmin2(U2(X2), U2(y)));
  }
  u32 E2 = __shfl_down(X2, 1); if (lane == 63) E2 = 0x11ff11ffu;

  u32 loA = 0, hiA = 0, loB = 0, hiB = 0;
  #pragma unroll
  for (int k = 0; k < 8; ++k) {
    us2 L = pmax2(U2(lm[k]), U2(E));
    us2 R = pmin2(U2(sm[k]), U2(E2));
    us2 ib = U2((u32)(c0 + k + 2048) * 0x10001u);
    us2 one = U2(0x10001u);
    us2 d1 = pmin2(pmin2((us2)(ib - L + one), (us2)(R - ib + one)), U2(0x007f007fu));
    u32 dd = B2(d1);
    int dA = (int)(dd & 0xffffu), dB = (int)(dd >> 16);
    int vA = (tp[k] & 0xffffu) ? dA : -dA;
    int vB = (tp[k] >> 16)     ? dB : -dB;
    u32 bA = (u32)(vA & 0xff), bB = (u32)(vB & 0xff);
    if (k < 4) { loA |= bA << (8 * k);       loB |= bB << (8 * k); }
    else       { hiA |= bA << (8 * (k - 4)); hiB |= bB << (8 * (k - 4)); }
  }
  ((uint2*)d1b)[(size_t)rowA * (WW / 8) + lane]       = make_uint2(loA, hiA);
  ((uint2*)d1b)[(size_t)(rowA + 1) * (WW / 8) + lane] = make_uint2(loB, hiB);
}

// ------------- Kernel B: column lower-envelope + all reductions --------------
// Per row-pair: read the UNION window pc/nc[e-4..e+4] once into registers
// (18 ds_read_b32), compute both parities from registers with cndmask
// class-select. Sentinel 127 pads OOB rows. inp prefetched before staging.
__global__ void __launch_bounds__(256, 8) k_env(const char* __restrict__ d1b,
                                                const float* __restrict__ inp,
                                                float* __restrict__ partS,
                                                u32* __restrict__ partM,
                                                float* __restrict__ partP,
                                                float* __restrict__ partTP,
                                                int* __restrict__ partT) {
  __shared__ u32 posT[64 * CDW];               // column-major u16, 2 rows/dword
  __shared__ u32 negT[64 * CDW];
  const int tid = threadIdx.x;
  const int cg = blockIdx.x, xt = blockIdx.y, b = blockIdx.z;
  const int w0 = cg * 64, x0 = xt * XT;
  const int wv = tid >> 6, lane = tid & 63;

  // prefetch inp rows (latency hidden under staging + barrier)
  const float* ip0 = inp + ((size_t)(b * HH + x0 + wv * 8)) * WW + w0 + lane;
  float fin[8];
  #pragma unroll
  for (int k = 0; k < 8; ++k) fin[k] = ip0[(size_t)k * WW];

  // transposed two-class staging: 256 units = (row-pair r2 0..31) x (c8 0..7)
  {
    int r2 = tid >> 3, c8 = tid & 7;
    int g0 = x0 - HALO + 2 * r2;
    const char* base = d1b + ((size_t)(b * HH)) * WW + w0 + c8 * 8;
    uint2 A = make_uint2(0, 0), Bv = make_uint2(0, 0);
    bool ok0 = (unsigned)g0 < (unsigned)HH;
    bool ok1 = (unsigned)(g0 + 1) < (unsigned)HH;
    if (ok0) A  = *(const uint2*)(base + (size_t)g0 * WW);
    if (ok1) Bv = *(const uint2*)(base + (size_t)(g0 + 1) * WW);
    u32 aw[2] = {A.x, A.y}, bw[2] = {Bv.x, Bv.y};
    #pragma unroll
    for (int j = 0; j < 8; ++j) {
      int sa = ((int)(aw[j >> 2] << ((3 - (j & 3)) * 8))) >> 24;  // sext byte
      int sb = ((int)(bw[j >> 2] << ((3 - (j & 3)) * 8))) >> 24;
      int vpa = ok0 ? max(sa, 0) : 127, vna = ok0 ? max(-sa, 0) : 127;
      int vpb = ok1 ? max(sb, 0) : 127, vnb = ok1 ? max(-sb, 0) : 127;
      int col = c8 * 8 + j;
      posT[col * CDW + r2] = (u32)vpa | ((u32)vpb << 16);
      negT[col * CDW + r2] = (u32)vna | ((u32)vnb << 16);
    }
  }
  __syncthreads();

  // packed dy^2 constants (even own row K0, odd own row K1)
  constexpr u32 K0[8] = {64|(49u<<16),36|(25u<<16),16|(9u<<16),4|(1u<<16),
                         0|(1u<<16),4|(9u<<16),16|(25u<<16),36|(49u<<16)};
  constexpr u32 K1[8] = {49|(36u<<16),25|(16u<<16),9|(4u<<16),1|(0u<<16),
                         1|(4u<<16),9|(16u<<16),25|(36u<<16),49|(64u<<16)};

  const u32* pc = posT + lane * CDW;
  const u32* nc = negT + lane * CDW;
  float aP = 0.f, aTP = 0.f, aS = 0.f;
  u32 aM = 0; int aC = 0;

  #pragma unroll 1
  for (int k2 = 0; k2 < 4; ++k2) {
    const int e = HALO / 2 + wv * 4 + k2;      // own row-pair dword index
    u32 wp[9], wn[9];
    #pragma unroll
    for (int j = 0; j < 9; ++j) { wp[j] = pc[e - 4 + j]; wn[j] = nc[e - 4 + j]; }
    const u32 pd = wp[4], nd = wn[4];
    const int vp0 = (int)(pd & 0xffffu), vn0 = (int)(nd & 0xffffu);
    const int vp1 = (int)(pd >> 16),     vn1 = (int)(nd >> 16);
    const bool fg0 = vp0 > 0, fg1 = vp1 > 0;
    const int uo0 = max(vp0, vn0), uo1 = max(vp1, vn1);
    us2 pb0 = U2(0xffffffffu), pb1 = pb0;
    #pragma unroll
    for (int j = 0; j < 8; ++j) {
      u32 c0w = fg0 ? wp[j] : wn[j];           // compile-time index, cndmask
      u32 c1w = fg1 ? wp[j + 1] : wn[j + 1];
      us2 m0 = U2(c0w), m1 = U2(c1w);
      pb0 = pmin2(pb0, (us2)(m0 * m0 + U2(K0[j])));
      pb1 = pmin2(pb1, (us2)(m1 * m1 + U2(K1[j])));
    }
    u32 best0 = min((u32)(uo0 * uo0), min((u32)pb0[0], (u32)pb0[1]));
    u32 best1 = min((u32)(uo1 * uo1), min((u32)pb1[0], (u32)pb1[1]));

    if (__any(max(uo0, uo1) > 8)) {            // rare exact fallback, dy 8..HALO
      const u32* cb0 = fg0 ? pc : nc;
      const u32* cb1 = fg1 ? pc : nc;
      const int rl0 = 2 * e, rl1 = 2 * e + 1;
      #pragma unroll 1
      for (int dy = 8; dy <= HALO; ++dy) {
        int q = dy * dy;
        {
          int rd = rl0 + dy, ru = rl0 - dy;
          u32 dd = cb0[rd >> 1], du = cb0[ru >> 1];
          int ud = (int)((dd >> ((rd & 1) * 16)) & 0xffffu);
          int uu = (int)((du >> ((ru & 1) * 16)) & 0xffffu);
          best0 = min(best0, (u32)(ud * ud + q));
          best0 = min(best0, (u32)(uu * uu + q));
        }
        {
          int rd = rl1 + dy, ru = rl1 - dy;
          u32 dd = cb1[rd >> 1], du = cb1[ru >> 1];
          int ud = (int)((dd >> ((rd & 1) * 16)) & 0xffffu);
          int uu = (int)((du >> ((ru & 1) * 16)) & 0xffffu);
          best1 = min(best1, (u32)(ud * ud + q));
          best1 = min(best1, (u32)(uu * uu + q));
        }
      }
    }

    {
      float D = sqrtf((float)best0);
      float p = 1.0f / (1.0f + __expf(-fin[2 * k2]));
      float pD = p * D;
      aP += p; aS += fg0 ? -pD : pD;
      if (fg0) { aTP += p; aC += 1; }
      aM = max(aM, best0);
    }
    {
      float D = sqrtf((float)best1);
      float p = 1.0f / (1.0f + __expf(-fin[2 * k2 + 1]));
      float pD = p * D;
      aP += p; aS += fg1 ? -pD : pD;
      if (fg1) { aTP += p; aC += 1; }
      aM = max(aM, best1);
    }
  }

  // wave reduce
  #pragma unroll
  for (int off = 32; off >= 1; off >>= 1) {
    aP  += __shfl_xor(aP, off);
    aTP += __shfl_xor(aTP, off);
    aS  += __shfl_xor(aS, off);
    aC  += __shfl_xor(aC, off);
    aM = max(aM, (u32)__shfl_xor((int)aM, off));
  }
  __shared__ float rP[4], rTP[4], rS[4];
  __shared__ u32 rM[4]; __shared__ int rC[4];
  if (lane == 0) { rP[wv] = aP; rTP[wv] = aTP; rS[wv] = aS; rM[wv] = aM; rC[wv] = aC; }
  __syncthreads();
  if (tid == 0) {
    int part = (b * 16 + xt) * 8 + cg;
    partP[part]  = rP[0] + rP[1] + rP[2] + rP[3];
    partTP[part] = rTP[0] + rTP[1] + rTP[2] + rTP[3];
    partS[part]  = rS[0] + rS[1] + rS[2] + rS[3];
    partM[part]  = max(max(rM[0], rM[1]), max(rM[2], rM[3]));
    partT[part]  = rC[0] + rC[1] + rC[2] + rC[3];
  }
}

// ---------------- Kernel C: finalize scalar loss -----------------------------
__global__ void __launch_bounds__(256) k_final(const float* __restrict__ partS,
                                               const u32* __restrict__ partM,
                                               const float* __restrict__ partP,
                                               const float* __restrict__ partTP,
                                               const int* __restrict__ partT,
                                               float* __restrict__ out) {
  const int t = threadIdx.x;
  const int img = t >> 4, j = t & 15;          // 16 threads per image
  float s = 0.f, p = 0.f, tp = 0.f; int tc = 0; u32 m2 = 0;
  #pragma unroll
  for (int q = 0; q < 8; ++q) {
    int e = img * 128 + j + q * 16;
    s += partS[e]; p += partP[e]; tp += partTP[e]; tc += partT[e];
    m2 = max(m2, partM[e]);
  }
  #pragma unroll
  for (int off = 8; off >= 1; off >>= 1) {
    s  += __shfl_xor(s, off);
    p  += __shfl_xor(p, off);
    tp += __shfl_xor(tp, off);
    tc += __shfl_xor(tc, off);
    m2 = max(m2, (u32)__shfl_xor((int)m2, off));
  }
  __shared__ float shC[16], shP[16], shTP[16]; __shared__ int shT[16];
  if (j == 0) {
    float bmax = sqrtf((float)m2);
    shC[img] = (tc > 0) ? (s / (bmax + 1e-8f)) : 0.0f;   // anypos guard
    shP[img] = p; shTP[img] = tp; shT[img] = tc;
  }
  __syncthreads();
  if (t == 0) {
    float sumP = 0.f, TP = 0.f, sumT = 0.f, bl = 0.f;
    for (int i = 0; i < 16; ++i) { sumP += shP[i]; TP += shTP[i]; sumT += (float)shT[i]; bl += shC[i]; }
    float FP = sumP - TP, FN = sumT - TP;
    float tv = (TP + 1.0f) / (TP + 0.3f * FP + 0.7f * FN + 1.0f);
    float ft = powf(1.0f - tv, 1.33f);
    float dice = (2.0f * TP + 1.0f) / (sumP + sumT + 1.0f);
    float dl = 1.0f - dice;
    float blm = bl / (float)NPIX;
    if (isnan(ft)) ft = 0.0f;
    if (isnan(dl)) dl = 0.0f;
    if (isnan(blm)) blm = 0.0f;
    out[0] = 0.5f * ft + 0.3f * dl + 0.2f * blm;
  }
}

extern "C" void kernel_launch(void* const* d_in, const int* in_sizes, int n_in,
                              void* d_out, int out_size, void* d_ws, size_t ws_size,
                              hipStream_t stream) {
  const float* inp = (const float*)d_in[0];
  const int* tg = (const int*)d_in[1];
  float* out = (float*)d_out;
  char* ws = (char*)d_ws;
  char* d1b = (char*)(ws + D1_OFF);
  float* partS  = (float*)(ws + PART_OFF);
  u32*   partM  = (u32*)(ws + PART_OFF + 8192);
  float* partP  = (float*)(ws + PART_OFF + 16384);
  float* partTP = (float*)(ws + PART_OFF + 24576);
  int*   partT  = (int*)(ws + PART_OFF + 32768);

  hipLaunchKernelGGL(k_rows, dim3(BB * HH / 8), dim3(256), 0, stream, tg, d1b);
  hipLaunchKernelGGL(k_env, dim3(WW / 64, HH / XT, BB), dim3(256), 0, stream,
                     d1b, inp, partS, partM, partP, partTP, partT);
  hipLaunchKernelGGL(k_final, dim3(1), dim3(256), 0, stream,
                     partS, partM, partP, partTP, partT, out);
}

// Round 11
// 26.647 us; speedup vs baseline: 2.8858x; 1.0988x over previous
//
#include <hip/hip_runtime.h>
#include <cstdint>

typedef unsigned short u16;
typedef unsigned int u32;
typedef unsigned short us2 __attribute__((ext_vector_type(2)));

constexpr int BB = 16, HH = 512, WW = 512;
constexpr int NPIX = BB * HH * WW;          // 4,194,304

// workspace layout (bytes)
constexpr size_t D1_OFF   = 0;                    // s8 signed d1 (cap 127), 4 MiB
constexpr size_t PART_OFF = (size_t)NPIX;

// envelope tiling
constexpr int HALO  = 16;                 // vertical halo (deep search cap)
constexpr int XT    = 32;                 // output rows per block
constexpr int TROWS = XT + 2 * HALO;      // 64 tile rows
constexpr int CDW   = TROWS / 2 + 1;      // 33 dwords per padded LDS column

__device__ __forceinline__ us2 pmax2(us2 a, us2 b) { return __builtin_elementwise_max(a, b); }
__device__ __forceinline__ us2 pmin2(us2 a, us2 b) { return __builtin_elementwise_min(a, b); }
__device__ __forceinline__ us2 U2(u32 x) { return __builtin_bit_cast(us2, x); }
__device__ __forceinline__ u32 B2(us2 x) { return __builtin_bit_cast(u32, x); }

// ---------------- Kernel A: packed dual-row 1D boundary scans ----------------
// Two image rows per wave, packed into u16 halves (biased +2048 positions).
// d1 = distance to nearest run boundary, capped 127; v = t ? +d1 : -d1 (s8).
// Output bit-identical to the single-row scan (verified absmax 0.0, R8/R10).
__global__ void __launch_bounds__(256) k_rows(const int* __restrict__ tg,
                                              char* __restrict__ d1b) {
  const int lane = threadIdx.x & 63;
  const int wv   = threadIdx.x >> 6;
  const int rowA = blockIdx.x * 8 + wv * 2;    // 1024 blocks, 2 rows per wave
  const int c0   = lane * 8;
  const int* rpA = tg + (size_t)rowA * WW + c0;
  const int* rpB = rpA + WW;
  int4 a0 = *(const int4*)rpA, a1 = *(const int4*)(rpA + 4);
  int4 b0 = *(const int4*)rpB, b1 = *(const int4*)(rpB + 4);
  int tA[8] = {a0.x, a0.y, a0.z, a0.w, a1.x, a1.y, a1.z, a1.w};
  int tB[8] = {b0.x, b0.y, b0.z, b0.w, b1.x, b1.y, b1.z, b1.w};
  u32 tp[8];
  #pragma unroll
  for (int k = 0; k < 8; ++k) tp[k] = (u32)tA[k] | ((u32)tB[k] << 16);
  u32 tprev = __shfl_up(tp[7], 1);  if (lane == 0)  tprev = tp[0];
  u32 tnext = __shfl_down(tp[0], 1); if (lane == 63) tnext = tp[7];

  // fwd: prefix max of (boundary-at-i ? i+2048 : 0), both rows packed u16
  u32 lm[8]; us2 m = U2(0);
  #pragma unroll
  for (int k = 0; k < 8; ++k) {
    u32 prev = k ? tp[k - 1] : tprev;
    us2 diff = U2(tp[k] ^ prev);               // 0/1 per half (targets are 0/1)
    us2 ib = U2((u32)(c0 + k + 2048) * 0x10001u);
    m = pmax2(m, (us2)(diff * ib));
    lm[k] = B2(m);
  }
  u32 X = B2(m);
  #pragma unroll
  for (int off = 1; off < 64; off <<= 1) {
    u32 y = __shfl_up(X, off);
    if (lane >= off) X = B2(pmax2(U2(X), U2(y)));
  }
  u32 E = __shfl_up(X, 1); if (lane == 0) E = 0;

  // bwd: suffix min of (boundary-at-i ? i+2048 : 4607)
  u32 sm[8]; us2 m2 = U2(0x11ff11ffu);
  #pragma unroll
  for (int k = 7; k >= 0; --k) {
    u32 nxt = (k < 7) ? tp[k + 1] : tnext;
    us2 diff = U2(tp[k] ^ nxt);
    us2 sb = U2((u32)(2559 - (c0 + k)) * 0x10001u);
    m2 = pmin2(m2, (us2)(U2(0x11ff11ffu) - (us2)(diff * sb)));
    sm[k] = B2(m2);
  }
  u32 X2 = B2(m2);
  #pragma unroll
  for (int off = 1; off < 64; off <<= 1) {
    u32 y = __shfl_down(X2, off);
    if (lane + off < 64) X2 = B2(pmin2(U2(X2), U2(y)));
  }
  u32 E2 = __shfl_down(X2, 1); if (lane == 63) E2 = 0x11ff11ffu;

  u32 loA = 0, hiA = 0, loB = 0, hiB = 0;
  #pragma unroll
  for (int k = 0; k < 8; ++k) {
    us2 L = pmax2(U2(lm[k]), U2(E));
    us2 R = pmin2(U2(sm[k]), U2(E2));
    us2 ib = U2((u32)(c0 + k + 2048) * 0x10001u);
    us2 one = U2(0x10001u);
    us2 d1 = pmin2(pmin2((us2)(ib - L + one), (us2)(R - ib + one)), U2(0x007f007fu));
    u32 dd = B2(d1);
    int dA = (int)(dd & 0xffffu), dB = (int)(dd >> 16);
    int vA = (tp[k] & 0xffffu) ? dA : -dA;
    int vB = (tp[k] >> 16)     ? dB : -dB;
    u32 bA = (u32)(vA & 0xff), bB = (u32)(vB & 0xff);
    if (k < 4) { loA |= bA << (8 * k);       loB |= bB << (8 * k); }
    else       { hiA |= bA << (8 * (k - 4)); hiB |= bB << (8 * (k - 4)); }
  }
  ((uint2*)d1b)[(size_t)rowA * (WW / 8) + lane]       = make_uint2(loA, hiA);
  ((uint2*)d1b)[(size_t)(rowA + 1) * (WW / 8) + lane] = make_uint2(loB, hiB);
}

// ------------- Kernel B: column lower-envelope + all reductions --------------
// (byte-identical to the R7 best: per-parity row_body, packed u16 window math,
// two-class tiles, sentinel 127, rare wave-uniform deep fallback)
template <int P>
__device__ __forceinline__ void row_body(
    int e, const u32* __restrict__ pc, const u32* __restrict__ nc,
    const float* __restrict__ ip,
    float& aP, float& aTP, float& aS, u32& aM, int& aC) {
  constexpr u16 KL[2][8] = {{64, 36, 16, 4, 0, 4, 16, 36},
                            {49, 25,  9, 1, 1, 9, 25, 49}};
  constexpr u16 KH[2][8] = {{49, 25,  9, 1, 1, 9, 25, 49},
                            {36, 16,  4, 0, 4, 16, 36, 64}};
  const u32 pd = pc[e], nd = nc[e];
  const int vp = (P == 0) ? (int)(pd & 0xffffu) : (int)(pd >> 16);
  const int vn = (P == 0) ? (int)(nd & 0xffffu) : (int)(nd >> 16);
  const bool fg = vp > 0;
  const int uo = max(vp, vn);                  // own-class 1D distance (one is 0)
  const u32* cb = fg ? pc : nc;                // search own-class tile
  const us2* cb2 = (const us2*)cb;
  const int s = e + P - 4;                     // window dwords s..s+7
  us2 bestpk = __builtin_bit_cast(us2, 0xffffffffu);
  #pragma unroll
  for (int i = 0; i < 8; ++i) {
    us2 w = cb2[s + i];
    us2 k = __builtin_bit_cast(us2, (u32)KL[P][i] | ((u32)KH[P][i] << 16));
    us2 cnd = (us2)(w * w + k);
    bestpk = __builtin_elementwise_min(bestpk, cnd);
  }
  u32 best = min((u32)(uo * uo), (u32)min((u32)bestpk[0], (u32)bestpk[1]));
  if (__any(uo > 8)) {                         // rare exact fallback, dy 8..HALO
    const int c = 2 * e + P;
    #pragma unroll 1
    for (int dy = 8; dy <= HALO; ++dy) {
      int rd = c + dy, ru = c - dy;
      u32 dd = cb[rd >> 1], du = cb[ru >> 1];
      int ud = (int)((dd >> ((rd & 1) * 16)) & 0xffffu);
      int uu = (int)((du >> ((ru & 1) * 16)) & 0xffffu);
      int q = dy * dy;
      best = min(best, (u32)(ud * ud + q));
      best = min(best, (u32)(uu * uu + q));
    }
  }
  float D = sqrtf((float)best);                // = posdis+negdis at this pixel
  float v = *ip;
  float p = 1.0f / (1.0f + __expf(-v));
  aP += p;
  if (fg) { aTP += p; aC += 1; aS -= p * D; } else { aS += p * D; }
  aM = max(aM, best);
}

__global__ void __launch_bounds__(256, 8) k_env(const char* __restrict__ d1b,
                                                const float* __restrict__ inp,
                                                float* __restrict__ partS,
                                                u32* __restrict__ partM,
                                                float* __restrict__ partP,
                                                float* __restrict__ partTP,
                                                int* __restrict__ partT) {
  __shared__ u32 posT[64 * CDW];               // column-major u16, 2 rows/dword
  __shared__ u32 negT[64 * CDW];
  const int tid = threadIdx.x;
  const int cg = blockIdx.x, xt = blockIdx.y, b = blockIdx.z;
  const int w0 = cg * 64, x0 = xt * XT;

  // transposed two-class staging: 256 units = (row-pair r2 0..31) x (c8 0..7)
  {
    int r2 = tid >> 3, c8 = tid & 7;
    int g0 = x0 - HALO + 2 * r2;
    const char* base = d1b + ((size_t)(b * HH)) * WW + w0 + c8 * 8;
    uint2 A = make_uint2(0, 0), Bv = make_uint2(0, 0);
    bool ok0 = (unsigned)g0 < (unsigned)HH;
    bool ok1 = (unsigned)(g0 + 1) < (unsigned)HH;
    if (ok0) A  = *(const uint2*)(base + (size_t)g0 * WW);
    if (ok1) Bv = *(const uint2*)(base + (size_t)(g0 + 1) * WW);
    u32 aw[2] = {A.x, A.y}, bw[2] = {Bv.x, Bv.y};
    #pragma unroll
    for (int j = 0; j < 8; ++j) {
      int sa = ((int)(aw[j >> 2] << ((3 - (j & 3)) * 8))) >> 24;  // sext byte
      int sb = ((int)(bw[j >> 2] << ((3 - (j & 3)) * 8))) >> 24;
      int vpa = ok0 ? max(sa, 0) : 127, vna = ok0 ? max(-sa, 0) : 127;
      int vpb = ok1 ? max(sb, 0) : 127, vnb = ok1 ? max(-sb, 0) : 127;
      int col = c8 * 8 + j;
      posT[col * CDW + r2] = (u32)vpa | ((u32)vpb << 16);
      negT[col * CDW + r2] = (u32)vna | ((u32)vnb << 16);
    }
  }
  __syncthreads();

  const int wv = tid >> 6, lane = tid & 63;
  const u32* pc = posT + lane * CDW;
  const u32* nc = negT + lane * CDW;
  const float* ip0 = inp + ((size_t)(b * HH + x0 + wv * 8)) * WW + w0 + lane;
  float aP = 0.f, aTP = 0.f, aS = 0.f;
  u32 aM = 0; int aC = 0;

  #pragma unroll 1
  for (int k2 = 0; k2 < 4; ++k2) {
    const int e = (HALO + wv * 8) / 2 + k2;    // own row-pair dword index
    row_body<0>(e, pc, nc, ip0 + (size_t)(2 * k2) * WW,     aP, aTP, aS, aM, aC);
    row_body<1>(e, pc, nc, ip0 + (size_t)(2 * k2 + 1) * WW, aP, aTP, aS, aM, aC);
  }

  // wave reduce
  #pragma unroll
  for (int off = 32; off >= 1; off >>= 1) {
    aP  += __shfl_xor(aP, off);
    aTP += __shfl_xor(aTP, off);
    aS  += __shfl_xor(aS, off);
    aC  += __shfl_xor(aC, off);
    aM = max(aM, (u32)__shfl_xor((int)aM, off));
  }
  __shared__ float rP[4], rTP[4], rS[4];
  __shared__ u32 rM[4]; __shared__ int rC[4];
  if (lane == 0) { rP[wv] = aP; rTP[wv] = aTP; rS[wv] = aS; rM[wv] = aM; rC[wv] = aC; }
  __syncthreads();
  if (tid == 0) {
    int part = (b * 16 + xt) * 8 + cg;
    partP[part]  = rP[0] + rP[1] + rP[2] + rP[3];
    partTP[part] = rTP[0] + rTP[1] + rTP[2] + rTP[3];
    partS[part]  = rS[0] + rS[1] + rS[2] + rS[3];
    partM[part]  = max(max(rM[0], rM[1]), max(rM[2], rM[3]));
    partT[part]  = rC[0] + rC[1] + rC[2] + rC[3];
  }
}

// ---------------- Kernel C: finalize scalar loss -----------------------------
__global__ void __launch_bounds__(256) k_final(const float* __restrict__ partS,
                                               const u32* __restrict__ partM,
                                               const float* __restrict__ partP,
                                               const float* __restrict__ partTP,
                                               const int* __restrict__ partT,
                                               float* __restrict__ out) {
  const int t = threadIdx.x;
  const int img = t >> 4, j = t & 15;          // 16 threads per image
  float s = 0.f, p = 0.f, tp = 0.f; int tc = 0; u32 m2 = 0;
  #pragma unroll
  for (int q = 0; q < 8; ++q) {
    int e = img * 128 + j + q * 16;
    s += partS[e]; p += partP[e]; tp += partTP[e]; tc += partT[e];
    m2 = max(m2, partM[e]);
  }
  #pragma unroll
  for (int off = 8; off >= 1; off >>= 1) {
    s  += __shfl_xor(s, off);
    p  += __shfl_xor(p, off);
    tp += __shfl_xor(tp, off);
    tc += __shfl_xor(tc, off);
    m2 = max(m2, (u32)__shfl_xor((int)m2, off));
  }
  __shared__ float shC[16], shP[16], shTP[16]; __shared__ int shT[16];
  if (j == 0) {
    float bmax = sqrtf((float)m2);
    shC[img] = (tc > 0) ? (s / (bmax + 1e-8f)) : 0.0f;   // anypos guard
    shP[img] = p; shTP[img] = tp; shT[img] = tc;
  }
  __syncthreads();
  if (t == 0) {
    float sumP = 0.f, TP = 0.f, sumT = 0.f, bl = 0.f;
    for (int i = 0; i < 16; ++i) { sumP += shP[i]; TP += shTP[i]; sumT += (float)shT[i]; bl += shC[i]; }
    float FP = sumP - TP, FN = sumT - TP;
    float tv = (TP + 1.0f) / (TP + 0.3f * FP + 0.7f * FN + 1.0f);
    float ft = powf(1.0f - tv, 1.33f);
    float dice = (2.0f * TP + 1.0f) / (sumP + sumT + 1.0f);
    float dl = 1.0f - dice;
    float blm = bl / (float)NPIX;
    if (isnan(ft)) ft = 0.0f;
    if (isnan(dl)) dl = 0.0f;
    if (isnan(blm)) blm = 0.0f;
    out[0] = 0.5f * ft + 0.3f * dl + 0.2f * blm;
  }
}

extern "C" void kernel_launch(void* const* d_in, const int* in_sizes, int n_in,
                              void* d_out, int out_size, void* d_ws, size_t ws_size,
                              hipStream_t stream) {
  const float* inp = (const float*)d_in[0];
  const int* tg = (const int*)d_in[1];
  float* out = (float*)d_out;
  char* ws = (char*)d_ws;
  char* d1b = (char*)(ws + D1_OFF);
  float* partS  = (float*)(ws + PART_OFF);
  u32*   partM  = (u32*)(ws + PART_OFF + 8192);
  float* partP  = (float*)(ws + PART_OFF + 16384);
  float* partTP = (float*)(ws + PART_OFF + 24576);
  int*   partT  = (int*)(ws + PART_OFF + 32768);

  hipLaunchKernelGGL(k_rows, dim3(BB * HH / 8), dim3(256), 0, stream, tg, d1b);
  hipLaunchKernelGGL(k_env, dim3(WW / 64, HH / XT, BB), dim3(256), 0, stream,
                     d1b, inp, partS, partM, partP, partTP, partT);
  hipLaunchKernelGGL(k_final, dim3(1), dim3(256), 0, stream,
                     partS, partM, partP, partTP, partT, out);
}